// Round 1
// 2489.258 us; speedup vs baseline: 1.5544x; 1.5544x over previous
//
#include <hip/hip_runtime.h>
#include <hip/hip_bf16.h>
#include <math.h>

#define NTOK 1024
#define DIM 2048
#define NH 16
#define HDIM 128
#define NE 64
#define NTOP 8
#define FF 1024
#define EPSI 1e-5f
#define ASCALE 0.08838834764831845f

typedef __attribute__((ext_vector_type(8))) short bh8;   // 8 bf16 in 4 VGPRs
typedef __attribute__((ext_vector_type(4))) float f4;

static __device__ __forceinline__ ushort f2bf(float f) {
  return __builtin_bit_cast(ushort, __float2bfloat16(f));
}

// ---------------- RMSNorm (one block per token row), fp32 out optional + bf16 out ----------------
__global__ __launch_bounds__(256) void k_rmsnorm(const float* __restrict__ in,
                                                 const float* __restrict__ w,
                                                 float* __restrict__ out,
                                                 ushort* __restrict__ outb) {
  int row = blockIdx.x, tid = threadIdx.x;
  const float* r = in + (size_t)row * DIM;
  float ss = 0.f;
  for (int i = tid; i < DIM; i += 256) { float v = r[i]; ss += v * v; }
#pragma unroll
  for (int o = 1; o < 64; o <<= 1) ss += __shfl_xor(ss, o, 64);
  __shared__ float red[4];
  if ((tid & 63) == 0) red[tid >> 6] = ss;
  __syncthreads();
  float rstd = rsqrtf((red[0] + red[1] + red[2] + red[3]) / (float)DIM + EPSI);
  if (out) {
    float* o_ = out + (size_t)row * DIM;
    ushort* ob = outb + (size_t)row * DIM;
    for (int i = tid; i < DIM; i += 256) {
      float v = r[i] * rstd * w[i];
      o_[i] = v; ob[i] = f2bf(v);
    }
  } else {
    ushort* ob = outb + (size_t)row * DIM;
    for (int i = tid; i < DIM; i += 256) ob[i] = f2bf(r[i] * rstd * w[i]);
  }
}

// ---------------- shared MFMA tile core: C128x128 += A(bf16)[*,K] @ W(f32)[N,K]^T ----------------
// 256 threads = 4 waves (2x2), each wave 64x64 via 4x4 frags of 16x16x32 bf16 MFMA.
// LDS rows padded to 40 bf16 (80B) -> frag ds_read_b128 is <=2-way on banks (free).
template <int KDIM>
static __device__ __forceinline__ void mm_tile(
    const ushort* __restrict__ Ap0, const ushort* __restrict__ Ap1,
    const float* __restrict__ Wp, ushort (*As)[40], ushort (*Bs)[40],
    int ar0, int ac0, int wrow, int wcol, int wr, int wc, int fr, int fq,
    f4 (&acc)[4][4]) {
  bh8 aR0 = *(const bh8*)Ap0;
  bh8 aR1 = *(const bh8*)Ap1;
  f4 wR[4];
#pragma unroll
  for (int i = 0; i < 4; i++) wR[i] = *(const f4*)(Wp + (size_t)(32 * i) * KDIM);
  for (int k0 = 0; k0 < KDIM; k0 += 32) {
    __syncthreads();  // previous frag reads done; LDS writable
    *(bh8*)&As[ar0][ac0] = aR0;
    *(bh8*)&As[ar0 + 64][ac0] = aR1;
#pragma unroll
    for (int i = 0; i < 4; i++) {
      ushort4 t = make_ushort4(f2bf(wR[i].x), f2bf(wR[i].y), f2bf(wR[i].z), f2bf(wR[i].w));
      *(ushort4*)&Bs[wrow + 32 * i][wcol] = t;
    }
    __syncthreads();
    if (k0 + 32 < KDIM) {  // prefetch next tile into regs; latency hides under MFMA
      aR0 = *(const bh8*)(Ap0 + k0 + 32);
      aR1 = *(const bh8*)(Ap1 + k0 + 32);
#pragma unroll
      for (int i = 0; i < 4; i++) wR[i] = *(const f4*)(Wp + (size_t)(32 * i) * KDIM + k0 + 32);
    }
    bh8 af[4], bf_[4];
#pragma unroll
    for (int m = 0; m < 4; m++) af[m] = *(const bh8*)&As[wr * 64 + m * 16 + fr][fq * 8];
#pragma unroll
    for (int n = 0; n < 4; n++) bf_[n] = *(const bh8*)&Bs[wc * 64 + n * 16 + fr][fq * 8];
#pragma unroll
    for (int m = 0; m < 4; m++)
#pragma unroll
      for (int n = 0; n < 4; n++)
        acc[m][n] = __builtin_amdgcn_mfma_f32_16x16x32_bf16(af[m], bf_[n], acc[m][n], 0, 0, 0);
  }
}

// ---------------- fused QKV projection: one launch, weight selected by n-tile ----------------
__global__ __launch_bounds__(256) void k_gemm_qkv(
    const ushort* __restrict__ A, const float* __restrict__ Wq,
    const float* __restrict__ Wk, const float* __restrict__ Wv,
    float* __restrict__ Cq, float* __restrict__ Ck, float* __restrict__ Cv) {
  __shared__ ushort As[128][40], Bs[128][40];
  int tid = threadIdx.x;
  int m0 = blockIdx.y * 128;
  int ng = blockIdx.x * 128;
  int wsel = ng >> 11, n0 = ng & 2047;
  const float* W = wsel == 0 ? Wq : wsel == 1 ? Wk : Wv;
  float* C = wsel == 0 ? Cq : wsel == 1 ? Ck : Cv;
  int lane = tid & 63, wid = tid >> 6;
  int wr = wid >> 1, wc = wid & 1, fr = lane & 15, fq = lane >> 4;
  int ar0 = tid >> 2, ac0 = (tid & 3) * 8;
  int wrow = tid >> 3, wcol = (tid & 7) * 4;
  const ushort* Ap0 = A + (size_t)(m0 + ar0) * DIM + ac0;
  const ushort* Ap1 = Ap0 + (size_t)64 * DIM;
  const float* Wp = W + (size_t)(n0 + wrow) * DIM + wcol;
  f4 acc[4][4];
  f4 z = {0.f, 0.f, 0.f, 0.f};
#pragma unroll
  for (int m = 0; m < 4; m++)
#pragma unroll
    for (int n = 0; n < 4; n++) acc[m][n] = z;
  mm_tile<DIM>(Ap0, Ap1, Wp, As, Bs, ar0, ac0, wrow, wcol, wr, wc, fr, fq, acc);
#pragma unroll
  for (int m = 0; m < 4; m++)
#pragma unroll
    for (int n = 0; n < 4; n++) {
      int row = m0 + wr * 64 + m * 16 + fq * 4;
      int col = n0 + wc * 64 + n * 16 + fr;
#pragma unroll
      for (int r = 0; r < 4; r++) C[(size_t)(row + r) * DIM + col] = acc[m][n][r];
    }
}

// ---------------- O projection + residual ----------------
__global__ __launch_bounds__(256) void k_gemm_o(
    const ushort* __restrict__ A, const float* __restrict__ W,
    const float* __restrict__ R, float* __restrict__ C) {
  __shared__ ushort As[128][40], Bs[128][40];
  int tid = threadIdx.x;
  int m0 = blockIdx.y * 128, n0 = blockIdx.x * 128;
  int lane = tid & 63, wid = tid >> 6;
  int wr = wid >> 1, wc = wid & 1, fr = lane & 15, fq = lane >> 4;
  int ar0 = tid >> 2, ac0 = (tid & 3) * 8;
  int wrow = tid >> 3, wcol = (tid & 7) * 4;
  const ushort* Ap0 = A + (size_t)(m0 + ar0) * DIM + ac0;
  const ushort* Ap1 = Ap0 + (size_t)64 * DIM;
  const float* Wp = W + (size_t)(n0 + wrow) * DIM + wcol;
  f4 acc[4][4];
  f4 z = {0.f, 0.f, 0.f, 0.f};
#pragma unroll
  for (int m = 0; m < 4; m++)
#pragma unroll
    for (int n = 0; n < 4; n++) acc[m][n] = z;
  mm_tile<DIM>(Ap0, Ap1, Wp, As, Bs, ar0, ac0, wrow, wcol, wr, wc, fr, fq, acc);
#pragma unroll
  for (int m = 0; m < 4; m++)
#pragma unroll
    for (int n = 0; n < 4; n++) {
      int row = m0 + wr * 64 + m * 16 + fq * 4;
      int col = n0 + wc * 64 + n * 16 + fr;
#pragma unroll
      for (int r = 0; r < 4; r++) {
        size_t o = (size_t)(row + r) * DIM + col;
        C[o] = acc[m][n][r] + R[o];
      }
    }
}

// ---------------- q/k full-D RMSNorm + RoPE + head-transpose; v transpose ----------------
__global__ __launch_bounds__(256) void k_qknorm_rope(
    const float* __restrict__ q, const float* __restrict__ k,
    const float* __restrict__ v, const float* __restrict__ qw,
    const float* __restrict__ kw, float* __restrict__ qr,
    float* __restrict__ kr, float* __restrict__ vr) {
  int s = blockIdx.x, tid = threadIdx.x;
  __shared__ float cst[64], snt[64];
  if (tid < 64) {
    float inv = powf(10000.f, -(float)tid / 64.f);
    float ang = (float)s * inv;
    cst[tid] = cosf(ang);
    snt[tid] = sinf(ang);
  }
  const float* qrow = q + (size_t)s * DIM;
  const float* krow = k + (size_t)s * DIM;
  const float* vrow = v + (size_t)s * DIM;
  float sq = 0.f, sk = 0.f;
  for (int i = tid; i < DIM; i += 256) {
    float a = qrow[i]; sq += a * a;
    float b = krow[i]; sk += b * b;
  }
#pragma unroll
  for (int o = 1; o < 64; o <<= 1) {
    sq += __shfl_xor(sq, o, 64);
    sk += __shfl_xor(sk, o, 64);
  }
  __shared__ float red[8];
  if ((tid & 63) == 0) { red[tid >> 6] = sq; red[4 + (tid >> 6)] = sk; }
  __syncthreads();
  float rq = rsqrtf((red[0] + red[1] + red[2] + red[3]) / (float)DIM + EPSI);
  float rk = rsqrtf((red[4] + red[5] + red[6] + red[7]) / (float)DIM + EPSI);
  for (int idx = tid; idx < NH * 64; idx += 256) {
    int hh = idx >> 6, i = idx & 63;
    float c = cst[i], sn = snt[i];
    int b = hh * HDIM + i;
    float q1 = qrow[b] * rq * qw[b];
    float q2 = qrow[b + 64] * rq * qw[b + 64];
    float k1 = krow[b] * rk * kw[b];
    float k2 = krow[b + 64] * rk * kw[b + 64];
    size_t ob = ((size_t)hh * NTOK + s) * HDIM + i;
    qr[ob] = q1 * c - q2 * sn;
    qr[ob + 64] = q2 * c + q1 * sn;
    kr[ob] = k1 * c - k2 * sn;
    kr[ob + 64] = k2 * c + k1 * sn;
  }
  for (int idx = tid; idx < DIM; idx += 256) {
    int hh = idx >> 7, d = idx & 127;
    vr[((size_t)hh * NTOK + s) * HDIM + d] = vrow[idx];
  }
}

// ---------------- causal flash attention, fp32, online softmax; bf16 ctx out ----------------
__global__ __launch_bounds__(256) void k_attn(const float* __restrict__ qr,
                                              const float* __restrict__ kr,
                                              const float* __restrict__ vr,
                                              ushort* __restrict__ ctx) {
  int h = blockIdx.y, qt = blockIdx.x;
  __shared__ __align__(16) float Ks[64][HDIM];
  __shared__ __align__(16) float Vs[64][HDIM];
  int tid = threadIdx.x;
  int ql = tid >> 2, sub = tid & 3;
  int qg = qt * 64 + ql;
  const float* qrow = qr + ((size_t)h * NTOK + qg) * HDIM + sub * 32;
  float4 q4[8], acc[8];
#pragma unroll
  for (int i = 0; i < 8; i++) {
    q4[i] = *(const float4*)(qrow + i * 4);
    acc[i] = make_float4(0.f, 0.f, 0.f, 0.f);
  }
  float m = -1e30f, l = 0.f;
  for (int kt = 0; kt <= qt; kt++) {
    __syncthreads();
    const float4* kg = (const float4*)(kr + ((size_t)h * NTOK + kt * 64) * HDIM);
    const float4* vg = (const float4*)(vr + ((size_t)h * NTOK + kt * 64) * HDIM);
#pragma unroll
    for (int i = 0; i < 8; i++) {
      int e4 = tid + i * 256;
      ((float4*)Ks)[e4] = kg[e4];
      ((float4*)Vs)[e4] = vg[e4];
    }
    __syncthreads();
    int jmax = min(64, qg - kt * 64 + 1);
    for (int j = 0; j < jmax; j++) {
      const float4* kj = (const float4*)&Ks[j][sub * 32];
      float sc = 0.f;
#pragma unroll
      for (int i = 0; i < 8; i++) {
        float4 kv = kj[i];
        sc += q4[i].x * kv.x + q4[i].y * kv.y + q4[i].z * kv.z + q4[i].w * kv.w;
      }
      sc += __shfl_xor(sc, 1, 64);
      sc += __shfl_xor(sc, 2, 64);
      sc *= ASCALE;
      float mn = fmaxf(m, sc);
      float al = __expf(m - mn);
      float p = __expf(sc - mn);
      l = l * al + p;
      const float4* vj = (const float4*)&Vs[j][sub * 32];
#pragma unroll
      for (int i = 0; i < 8; i++) {
        float4 vv = vj[i];
        acc[i].x = acc[i].x * al + p * vv.x;
        acc[i].y = acc[i].y * al + p * vv.y;
        acc[i].z = acc[i].z * al + p * vv.z;
        acc[i].w = acc[i].w * al + p * vv.w;
      }
      m = mn;
    }
  }
  float invl = 1.f / l;
  ushort* crow = ctx + (size_t)qg * DIM + h * HDIM + sub * 32;
#pragma unroll
  for (int i = 0; i < 8; i++) {
    float4 o = acc[i];
    ushort4 t = make_ushort4(f2bf(o.x * invl), f2bf(o.y * invl),
                             f2bf(o.z * invl), f2bf(o.w * invl));
    *(ushort4*)(crow + i * 4) = t;
  }
}

// ---------------- router: logits + softmax + top-8 + expert lists ----------------
__global__ void k_zero_counts(int* counts) {
  if (threadIdx.x < NE) counts[threadIdx.x] = 0;
}

__global__ __launch_bounds__(256) void k_router(const float* __restrict__ h,
                                                const float* __restrict__ rw,
                                                float* __restrict__ topw,
                                                int* __restrict__ lists,
                                                int* __restrict__ counts) {
  int s = blockIdx.x, tid = threadIdx.x;
  int e = tid >> 2, sub = tid & 3;
  const float* hrow = h + (size_t)s * DIM;
  const float* wrow = rw + (size_t)e * DIM;
  float p = 0.f;
  for (int i = sub * 4; i < DIM; i += 16) {
    float4 hv = *(const float4*)(hrow + i);
    float4 wv = *(const float4*)(wrow + i);
    p += hv.x * wv.x + hv.y * wv.y + hv.z * wv.z + hv.w * wv.w;
  }
  p += __shfl_xor(p, 1, 64);
  p += __shfl_xor(p, 2, 64);
  __shared__ float probs[NE];
  if (sub == 0) probs[e] = p;
  __syncthreads();
  if (tid == 0) {
    float mx = -1e30f;
    for (int i = 0; i < NE; i++) mx = fmaxf(mx, probs[i]);
    float sum = 0.f;
    for (int i = 0; i < NE; i++) { probs[i] = __expf(probs[i] - mx); sum += probs[i]; }
    float inv = 1.f / sum;
    for (int kk = 0; kk < NTOP; kk++) {
      float best = -1.f; int bi = 0;
      for (int i = 0; i < NE; i++)
        if (probs[i] > best) { best = probs[i]; bi = i; }
      topw[s * NTOP + kk] = best * inv;
      probs[bi] = -1.f;
      int slot = atomicAdd(&counts[bi], 1);
      lists[bi * NTOK + slot] = s * NTOP + kk;  // store g = s*8+k
    }
  }
}

// ---------------- MoE gate+up fused MFMA GEMM (gathered rows) + silu*up -> bf16 act ----------------
__global__ __launch_bounds__(256) void k_moe_gate_up(
    const ushort* __restrict__ hb, const float* __restrict__ gate,
    const float* __restrict__ up, const int* __restrict__ lists,
    const int* __restrict__ counts, ushort* __restrict__ act) {
  int e = blockIdx.z;
  int nt = counts[e];
  int m0 = blockIdx.y * 128;
  if (m0 >= nt) return;
  __shared__ ushort As[128][40], Gs[128][40], Us[128][40];
  int f0 = blockIdx.x * 128;
  int tid = threadIdx.x;
  int lane = tid & 63, wid = tid >> 6;
  int wr = wid >> 1, wc = wid & 1, fr = lane & 15, fq = lane >> 4;
  int ar0 = tid >> 2, ac0 = (tid & 3) * 8;
  int wrow = tid >> 3, wcol = (tid & 7) * 4;
  int r0 = m0 + ar0, r1 = r0 + 64;
  int g0 = lists[e * NTOK + (r0 < nt ? r0 : nt - 1)];
  int g1 = lists[e * NTOK + (r1 < nt ? r1 : nt - 1)];
  const ushort* Ap0 = hb + (size_t)(g0 >> 3) * DIM + ac0;
  const ushort* Ap1 = hb + (size_t)(g1 >> 3) * DIM + ac0;
  const float* Gp = gate + ((size_t)e * FF + f0 + wrow) * DIM + wcol;
  const float* Up = up + ((size_t)e * FF + f0 + wrow) * DIM + wcol;
  f4 ag[4][4], au[4][4];
  f4 z = {0.f, 0.f, 0.f, 0.f};
#pragma unroll
  for (int m = 0; m < 4; m++)
#pragma unroll
    for (int n = 0; n < 4; n++) { ag[m][n] = z; au[m][n] = z; }
  bh8 aR0 = *(const bh8*)Ap0;
  bh8 aR1 = *(const bh8*)Ap1;
  f4 gR[4], uR[4];
#pragma unroll
  for (int i = 0; i < 4; i++) {
    gR[i] = *(const f4*)(Gp + (size_t)(32 * i) * DIM);
    uR[i] = *(const f4*)(Up + (size_t)(32 * i) * DIM);
  }
  for (int k0 = 0; k0 < DIM; k0 += 32) {
    __syncthreads();
    *(bh8*)&As[ar0][ac0] = aR0;
    *(bh8*)&As[ar0 + 64][ac0] = aR1;
#pragma unroll
    for (int i = 0; i < 4; i++) {
      ushort4 tg = make_ushort4(f2bf(gR[i].x), f2bf(gR[i].y), f2bf(gR[i].z), f2bf(gR[i].w));
      *(ushort4*)&Gs[wrow + 32 * i][wcol] = tg;
      ushort4 tu = make_ushort4(f2bf(uR[i].x), f2bf(uR[i].y), f2bf(uR[i].z), f2bf(uR[i].w));
      *(ushort4*)&Us[wrow + 32 * i][wcol] = tu;
    }
    __syncthreads();
    if (k0 + 32 < DIM) {
      aR0 = *(const bh8*)(Ap0 + k0 + 32);
      aR1 = *(const bh8*)(Ap1 + k0 + 32);
#pragma unroll
      for (int i = 0; i < 4; i++) {
        gR[i] = *(const f4*)(Gp + (size_t)(32 * i) * DIM + k0 + 32);
        uR[i] = *(const f4*)(Up + (size_t)(32 * i) * DIM + k0 + 32);
      }
    }
    bh8 af[4], bg_[4], bu_[4];
#pragma unroll
    for (int m = 0; m < 4; m++) af[m] = *(const bh8*)&As[wr * 64 + m * 16 + fr][fq * 8];
#pragma unroll
    for (int n = 0; n < 4; n++) {
      bg_[n] = *(const bh8*)&Gs[wc * 64 + n * 16 + fr][fq * 8];
      bu_[n] = *(const bh8*)&Us[wc * 64 + n * 16 + fr][fq * 8];
    }
#pragma unroll
    for (int m = 0; m < 4; m++)
#pragma unroll
      for (int n = 0; n < 4; n++) {
        ag[m][n] = __builtin_amdgcn_mfma_f32_16x16x32_bf16(af[m], bg_[n], ag[m][n], 0, 0, 0);
        au[m][n] = __builtin_amdgcn_mfma_f32_16x16x32_bf16(af[m], bu_[n], au[m][n], 0, 0, 0);
      }
  }
#pragma unroll
  for (int m = 0; m < 4; m++) {
#pragma unroll
    for (int r = 0; r < 4; r++) {
      int mrow = m0 + wr * 64 + m * 16 + fq * 4 + r;
      if (mrow < nt) {
        int gg = lists[e * NTOK + mrow];
        ushort* arow = act + (size_t)gg * FF + f0 + wc * 64 + fr;
#pragma unroll
        for (int n = 0; n < 4; n++) {
          float gv = ag[m][n][r], uv = au[m][n][r];
          float sv = gv / (1.f + __expf(-gv)) * uv;
          arow[n * 16] = f2bf(sv);
        }
      }
    }
  }
}

// ---------------- MoE down MFMA GEMM (gathered rows) + weighted scatter-add ----------------
__global__ __launch_bounds__(256) void k_moe_down(
    const ushort* __restrict__ act, const float* __restrict__ down,
    const int* __restrict__ lists, const int* __restrict__ counts,
    const float* __restrict__ topw, float* __restrict__ out) {
  int e = blockIdx.z;
  int nt = counts[e];
  int m0 = blockIdx.y * 128;
  if (m0 >= nt) return;
  __shared__ ushort As[128][40], Bs[128][40];
  int n0 = blockIdx.x * 128;
  int tid = threadIdx.x;
  int lane = tid & 63, wid = tid >> 6;
  int wr = wid >> 1, wc = wid & 1, fr = lane & 15, fq = lane >> 4;
  int ar0 = tid >> 2, ac0 = (tid & 3) * 8;
  int wrow = tid >> 3, wcol = (tid & 7) * 4;
  int r0 = m0 + ar0, r1 = r0 + 64;
  int g0 = lists[e * NTOK + (r0 < nt ? r0 : nt - 1)];
  int g1 = lists[e * NTOK + (r1 < nt ? r1 : nt - 1)];
  const ushort* Ap0 = act + (size_t)g0 * FF + ac0;
  const ushort* Ap1 = act + (size_t)g1 * FF + ac0;
  const float* Wp = down + ((size_t)e * DIM + n0 + wrow) * FF + wcol;
  f4 acc[4][4];
  f4 z = {0.f, 0.f, 0.f, 0.f};
#pragma unroll
  for (int m = 0; m < 4; m++)
#pragma unroll
    for (int n = 0; n < 4; n++) acc[m][n] = z;
  mm_tile<FF>(Ap0, Ap1, Wp, As, Bs, ar0, ac0, wrow, wcol, wr, wc, fr, fq, acc);
#pragma unroll
  for (int m = 0; m < 4; m++) {
#pragma unroll
    for (int r = 0; r < 4; r++) {
      int mrow = m0 + wr * 64 + m * 16 + fq * 4 + r;
      if (mrow < nt) {
        int gg = lists[e * NTOK + mrow];
        int s = gg >> 3;
        float wgt = topw[gg];
        float* orow = out + (size_t)s * DIM + n0 + wc * 64 + fr;
#pragma unroll
        for (int n = 0; n < 4; n++) atomicAdd(&orow[n * 16], wgt * acc[m][n][r]);
      }
    }
  }
}

extern "C" void kernel_launch(void* const* d_in, const int* in_sizes, int n_in,
                              void* d_out, int out_size, void* d_ws, size_t ws_size,
                              hipStream_t stream) {
  const float* x   = (const float*)d_in[0];
  const float* iln = (const float*)d_in[1];
  const float* qw  = (const float*)d_in[2];
  const float* qnw = (const float*)d_in[3];
  const float* kw  = (const float*)d_in[4];
  const float* knw = (const float*)d_in[5];
  const float* vw  = (const float*)d_in[6];
  const float* ow  = (const float*)d_in[7];
  const float* pln = (const float*)d_in[8];
  const float* rw  = (const float*)d_in[9];
  const float* gw  = (const float*)d_in[10];
  const float* uw  = (const float*)d_in[11];
  const float* dw  = (const float*)d_in[12];
  float* out = (float*)d_out;
  float* ws = (float*)d_ws;

  const size_t M2 = (size_t)NTOK * DIM;  // 2M floats
  // ws layout (7 slots of M2 floats, aliased across phases; ~56 MB total):
  float* qb = ws + 0 * M2;                 // later: h (post-LN fp32)
  float* kb = ws + 1 * M2;                 // later: ctxb (1M fl) + topw/lists/counts
  float* vb = ws + 2 * M2;                 // later: act start
  float* qr = ws + 3 * M2;                 // act spans vb+qr exactly (4M floats)
  float* kr = ws + 4 * M2;
  float* vr = ws + 5 * M2;
  ushort* xnb = (ushort*)(ws + 6 * M2);    // 2M ushorts
  ushort* hb  = xnb + M2;                  // 2M ushorts (second half of slot 6)
  ushort* ctxb = (ushort*)kb;              // 2M ushorts = first 1M floats of kb
  float* topw = kb + M2 / 2;               // 8192 floats
  int* lists = (int*)(topw + NTOK * NTOP); // 64*1024 ints
  int* counts = lists + NE * NTOK;         // 64 ints
  float* h = qb;
  ushort* act = (ushort*)vb;               // 8192*1024 ushorts = 4M floats (vb+qr)

  // 1. input RMSNorm -> bf16 only
  k_rmsnorm<<<NTOK, 256, 0, stream>>>(x, iln, nullptr, xnb);
  // 2. fused Q,K,V projections (bf16 MFMA, in-kernel weight cvt)
  k_gemm_qkv<<<dim3(48, 8), 256, 0, stream>>>(xnb, qw, kw, vw, qb, kb, vb);
  // 3. q/k norm + RoPE + head transpose, v transpose
  k_qknorm_rope<<<NTOK, 256, 0, stream>>>(qb, kb, vb, qnw, knw, qr, kr, vr);
  // 4. causal attention -> ctx bf16 ([s][h*128+d] layout)
  k_attn<<<dim3(NTOK / 64, NH), 256, 0, stream>>>(qr, kr, vr, ctxb);
  // 5. O projection + residual -> out holds x_res
  k_gemm_o<<<dim3(16, 8), 256, 0, stream>>>(ctxb, ow, x, out);
  // 6. post-attention RMSNorm -> h fp32 (router) + hb bf16 (MoE A)
  k_rmsnorm<<<NTOK, 256, 0, stream>>>(out, pln, h, hb);
  // 7. routing
  k_zero_counts<<<1, 64, 0, stream>>>(counts);
  k_router<<<NTOK, 256, 0, stream>>>(h, rw, topw, lists, counts);
  // 8. sparse MoE: fused gate/up MFMA + silu*up -> act (bf16)
  k_moe_gate_up<<<dim3(FF / 128, NTOK / 128, NE), 256, 0, stream>>>(hb, gw, uw, lists, counts, act);
  // 9. down proj MFMA, weighted scatter-add into out (out += moe)
  k_moe_down<<<dim3(DIM / 128, NTOK / 128, NE), 256, 0, stream>>>(act, dw, lists, counts, topw, out);
}